// Round 9
// baseline (201.402 us; speedup 1.0000x reference)
//
#include <hip/hip_runtime.h>

#define HID 896
#define NH 14
#define NKV 2
#define NREP 7
#define SEQ 2048
#define BT 2
#define NTOK (BT*SEQ)
#define CSCALE 0.18033688011112042f   // (1/8) * log2(e), folded into Q at projection

typedef __attribute__((ext_vector_type(8))) short bf16x8;
typedef __attribute__((ext_vector_type(8))) unsigned short u16x8;
typedef __attribute__((ext_vector_type(4))) float fx4;
typedef __attribute__((ext_vector_type(4))) short s16x4;
typedef _Float16 f16x4 __attribute__((ext_vector_type(4)));
typedef __fp16 fp16x2 __attribute__((ext_vector_type(2)));   // cvt_pkrtz return type

#define LDA 136   // LDS row stride (shorts) for BK=128 tiles; 68 dw/row -> bank rotate 4 (as 72)

__device__ __forceinline__ unsigned short f2b(float x){
  union { float f; unsigned u; } a; a.f = x;
  unsigned r = a.u + 0x7FFFu + ((a.u >> 16) & 1u);   // RNE
  return (unsigned short)(r >> 16);
}
__device__ __forceinline__ unsigned short f2h(float x){
  union { _Float16 h; unsigned short u; } a; a.h = (_Float16)x; return a.u;
}

// ------- fp32->bf16 convert (jobs 0..3: weights) + RoPE table build (job 4) -------
__global__ __launch_bounds__(256) void cvt_kernel(
    const float* __restrict__ s0, const float* __restrict__ s1,
    const float* __restrict__ s2, const float* __restrict__ s3,
    unsigned short* __restrict__ d0, unsigned short* __restrict__ d1,
    unsigned short* __restrict__ d2, unsigned short* __restrict__ d3,
    int c0, int c1, int c2, int c3,
    float2* __restrict__ tab)
{
  if (blockIdx.y == 4){
    for (int i = blockIdx.x*256 + threadIdx.x; i < SEQ*32; i += gridDim.x*256){
      int s = i >> 5, d = i & 31;
      float f = (float)s * exp2f(-(float)d * 0.62286151779138041f);
      float sv, cv; sincosf(f, &sv, &cv);
      tab[i] = make_float2(cv, sv);
    }
    return;
  }
  const float* s; unsigned short* d; int c;
  switch (blockIdx.y){
    case 0: s=s0; d=d0; c=c0; break;
    case 1: s=s1; d=d1; c=c1; break;
    case 2: s=s2; d=d2; c=c2; break;
    default: s=s3; d=d3; c=c3; break;
  }
  for (int i = (blockIdx.x*256 + threadIdx.x)*8; i < c; i += gridDim.x*2048){
    float4 a = *(const float4*)(s + i);
    float4 b = *(const float4*)(s + i + 4);
    u16x8 o;
    o[0]=f2b(a.x); o[1]=f2b(a.y); o[2]=f2b(a.z); o[3]=f2b(a.w);
    o[4]=f2b(b.x); o[5]=f2b(b.y); o[6]=f2b(b.z); o[7]=f2b(b.w);
    *(u16x8*)(d + i) = o;
  }
}

// ---------------- QKV projection GEMM (64x128 tile, BK=128) + bias + table-RoPE ----------------
// A = hidden fp32 (inline-converted), B = WQKV bf16 [1152,896]. grid (64,9), block 256 (2x2 waves).
// 7 k-iters (14 barrier rounds, halved vs BK=64). Q outputs pre-scaled by CSCALE.
__global__ __launch_bounds__(256) void qkv_gemm_kernel(
    const float* __restrict__ hidden, const unsigned short* __restrict__ Bw,
    const float* __restrict__ bq, const float* __restrict__ bk, const float* __restrict__ bv,
    const int* __restrict__ pos, const float2* __restrict__ tab,
    unsigned short* __restrict__ qo, unsigned short* __restrict__ ko,
    unsigned short* __restrict__ vt)
{
  __shared__ short As[64*LDA];    // 17.4 KB
  __shared__ short Bs[128*LDA];   // 34.8 KB
  const int tid = threadIdx.x;
  const int bm = blockIdx.x, bn = blockIdx.y;
  const int w = tid >> 6, l = tid & 63, l15 = l & 15, q4 = l >> 4;
  const int wm = w >> 1, wn = w & 1;

  fx4 acc[2][4] = {};

  const int arow = tid >> 2, acol = (tid & 3)*32;            // A: 64 rows x 128 cols
  const int brow = tid >> 1, bcol = (tid & 1)*64;            // B: 128 rows x 128 cols
  const float* Agf = hidden + (size_t)(bm*64 + arow)*HID + acol;
  const unsigned short* Bg = Bw + (size_t)(bn*128 + brow)*HID + bcol;

  float4 a4[8]; u16x8 br[8];
#pragma unroll
  for (int p = 0; p < 8; p++) a4[p] = *(const float4*)(Agf + p*4);
#pragma unroll
  for (int p = 0; p < 8; p++) br[p] = *(const u16x8*)(Bg + p*8);

  for (int kt = 0; kt < 7; kt++){
#pragma unroll
    for (int p = 0; p < 4; p++){
      u16x8 av;
      av[0]=f2b(a4[2*p].x); av[1]=f2b(a4[2*p].y); av[2]=f2b(a4[2*p].z); av[3]=f2b(a4[2*p].w);
      av[4]=f2b(a4[2*p+1].x); av[5]=f2b(a4[2*p+1].y); av[6]=f2b(a4[2*p+1].z); av[7]=f2b(a4[2*p+1].w);
      *(u16x8*)&As[arow*LDA + acol + p*8] = av;
    }
#pragma unroll
    for (int p = 0; p < 8; p++) *(u16x8*)&Bs[brow*LDA + bcol + p*8] = br[p];
    __syncthreads();
    if (kt < 6){
      const int ko_ = (kt+1)*128;
#pragma unroll
      for (int p = 0; p < 8; p++) a4[p] = *(const float4*)(Agf + ko_ + p*4);
#pragma unroll
      for (int p = 0; p < 8; p++) br[p] = *(const u16x8*)(Bg + ko_ + p*8);
    }
#pragma unroll
    for (int ks = 0; ks < 4; ks++){
      bf16x8 af[2], bf[4];
#pragma unroll
      for (int mt = 0; mt < 2; mt++)
        af[mt] = *(bf16x8*)&As[(wm*32 + mt*16 + l15)*LDA + ks*32 + q4*8];
#pragma unroll
      for (int nt = 0; nt < 4; nt++)
        bf[nt] = *(bf16x8*)&Bs[(wn*64 + nt*16 + l15)*LDA + ks*32 + q4*8];
#pragma unroll
      for (int mt = 0; mt < 2; mt++)
#pragma unroll
        for (int nt = 0; nt < 4; nt++)
          acc[mt][nt] = __builtin_amdgcn_mfma_f32_16x16x32_bf16(af[mt], bf[nt], acc[mt][nt], 0,0,0);
    }
    __syncthreads();
  }

  const int hu = bn*2 + wn;
  const float* bias; int kind, hloc;
  if (hu < NH)      { bias = bq + hu*64;      kind = 0; hloc = hu; }
  else if (hu < 16) { bias = bk + (hu-NH)*64; kind = 1; hloc = hu-NH; }
  else              { bias = bv + (hu-16)*64; kind = 2; hloc = hu-16; }
  float bl[4];
#pragma unroll
  for (int nt = 0; nt < 4; nt++) bl[nt] = bias[nt*16 + l15];

  if (kind == 2){
#pragma unroll
    for (int mt = 0; mt < 2; mt++)
#pragma unroll
      for (int j = 0; j < 4; j++){
        int grow = bm*64 + wm*32 + mt*16 + q4*4 + j;
        int b = grow >> 11, s = grow & (SEQ-1);
        int tile = s >> 6, key = s & 63;
        unsigned short* dst = vt + (size_t)(((b*NKV + hloc)*(SEQ/64) + tile)*4096);
#pragma unroll
        for (int nt = 0; nt < 4; nt++)
          dst[(nt*16 + l15)*64 + key] = f2h(acc[mt][nt][j] + bl[nt]);
      }
  } else {
    const float qs = (kind == 0) ? CSCALE : 1.0f;
#pragma unroll
    for (int mt = 0; mt < 2; mt++)
#pragma unroll
      for (int j = 0; j < 4; j++){
        int grow = bm*64 + wm*32 + mt*16 + q4*4 + j;
        int b = grow >> 11, s = grow & (SEQ-1);
        int p = pos[grow];
        const float2* rp = tab + p*32 + l15;
        float2 cs0 = rp[0], cs1 = rp[16];
        unsigned short* dst = (kind == 0)
            ? qo + ((size_t)(b*NH  + hloc)*SEQ + s)*64
            : ko + ((size_t)(b*NKV + hloc)*SEQ + s)*64;
        float x1 = acc[mt][0][j] + bl[0], x2 = acc[mt][2][j] + bl[2];
        float y1 = acc[mt][1][j] + bl[1], y2 = acc[mt][3][j] + bl[3];
        dst[l15]      = f2b((x1*cs0.x - x2*cs0.y)*qs);
        dst[16 + l15] = f2b((y1*cs1.x - y2*cs1.y)*qs);
        dst[32 + l15] = f2b((x2*cs0.x + x1*cs0.y)*qs);
        dst[48 + l15] = f2b((y2*cs1.x + y1*cs1.y)*qs);
      }
  }
}

// -------- per-tile softmax + PV update (S^T orientation; CSCALE pre-folded into Q) --------
__device__ __forceinline__ void smax_pv(
    const fx4* s, bool diag, int wl, int q4,
    float& m_run, float& l_run, fx4* o, const f16x4 vf[4][4])
{
  float tv[16];
#pragma unroll
  for (int tl = 0; tl < 4; tl++)
#pragma unroll
    for (int j = 0; j < 4; j++){
      float x = s[tl][j];
      if (diag && (tl*16 + q4*4 + j > wl)) x = -1e30f;
      tv[tl*4+j] = x;
    }
  float mx = tv[0];
#pragma unroll
  for (int i = 1; i < 16; i++) mx = fmaxf(mx, tv[i]);
  mx = fmaxf(mx, __shfl_xor(mx, 16));
  mx = fmaxf(mx, __shfl_xor(mx, 32));
  float mn = fmaxf(m_run, mx);
  float al = exp2f(m_run - mn);
  m_run = mn;
  float p[16], rs = 0.f;
#pragma unroll
  for (int i = 0; i < 16; i++){ p[i] = exp2f(tv[i] - mn); rs += p[i]; }
  rs += __shfl_xor(rs, 16);
  rs += __shfl_xor(rs, 32);
  l_run = l_run*al + rs;
#pragma unroll
  for (int nt = 0; nt < 4; nt++)
#pragma unroll
    for (int j = 0; j < 4; j++) o[nt][j] *= al;
  f16x4 pf[4];
#pragma unroll
  for (int tl = 0; tl < 4; tl++){
    union { f16x4 v; fp16x2 h[2]; } u;
    u.h[0] = __builtin_amdgcn_cvt_pkrtz(p[tl*4+0], p[tl*4+1]);
    u.h[1] = __builtin_amdgcn_cvt_pkrtz(p[tl*4+2], p[tl*4+3]);
    pf[tl] = u.v;
  }
#pragma unroll
  for (int nt = 0; nt < 4; nt++)
#pragma unroll
    for (int tl = 0; tl < 4; tl++)
      o[nt] = __builtin_amdgcn_mfma_f32_16x16x16f16(vf[nt][tl], pf[tl], o[nt], 0,0,0);
}

// ---------------- flash attention (R7 paired + split-K; best measured 59.4us) ----------------
// grid (16, NH, BT), block 512 (8 waves). Group g = w>>2 handles k-tiles with parity g.
// Block covers q-tiles tlo=bx and thi=31-bx; wave wi owns 16 q-rows of each.
__global__ __launch_bounds__(512) void attn_kernel(
    const unsigned short* __restrict__ q, const unsigned short* __restrict__ k,
    const unsigned short* __restrict__ vt, unsigned short* __restrict__ ao)
{
  __shared__ short SB[4*64*72];            // Ks pair | Vt pair; merge buffer at end
  short* KsB = SB;
  short* VtB = SB + 2*64*72;

  const int tid = threadIdx.x;
  const int w = tid >> 6, l = tid & 63, l15 = l & 15, q4 = l >> 4;
  const int g = w >> 2, wi = w & 3;
  const int tlo = blockIdx.x, thi = 31 - tlo;
  const int h = blockIdx.y, b = blockIdx.z, kvh = h / NREP;
  const int wl = wi*16 + l15;

  const unsigned short* qbase = q + ((size_t)(b*NH + h)*SEQ)*64;
  const unsigned short* qpA = qbase + (size_t)(thi*64 + wl)*64;
  const unsigned short* qpB = qbase + (size_t)(tlo*64 + wl)*64;
  bf16x8 qA0 = *(const bf16x8*)(qpA + q4*8), qA1 = *(const bf16x8*)(qpA + 32 + q4*8);
  bf16x8 qB0 = *(const bf16x8*)(qpB + q4*8), qB1 = *(const bf16x8*)(qpB + 32 + q4*8);

  fx4 oA[4] = {}, oB[4] = {};
  float mA = -1e30f, lA = 0.f, mB = -1e30f, lB = 0.f;

  const unsigned short* kbase = k  + ((size_t)(b*NKV + kvh)*SEQ)*64;
  const unsigned short* vbase = vt + (size_t)((b*NKV + kvh)*(SEQ/64))*4096;

  const int P = (thi + 2) >> 1;

  u16x8 kreg[2], vreg[2];
#pragma unroll
  for (int p = 0; p < 2; p++){
    int idx = p*512 + tid, tile = idx >> 9, off = idx & 511;
    kreg[p] = *(const u16x8*)(kbase + (size_t)tile*4096 + off*8);
    vreg[p] = *(const u16x8*)(vbase + (size_t)tile*4096 + off*8);
  }

  for (int si = 0; si < P; si++){
#pragma unroll
    for (int p = 0; p < 2; p++){
      int idx = p*512 + tid, tile = idx >> 9, off = idx & 511;
      int rr = off >> 3, g8 = off & 7;
      *(u16x8*)&KsB[tile*4608 + rr*72 + g8*8] = kreg[p];
      *(u16x8*)&VtB[tile*4608 + rr*72 + g8*8] = vreg[p];
    }
    __syncthreads();

    if (si + 1 < P){
      const int k0n = 2*(si+1);
#pragma unroll
      for (int p = 0; p < 2; p++){
        int idx = p*512 + tid, tile = idx >> 9, off = idx & 511;
        int tk = k0n + tile; if (tk > thi) tk = thi;
        kreg[p] = *(const u16x8*)(kbase + (size_t)tk*4096 + off*8);
        vreg[p] = *(const u16x8*)(vbase + (size_t)tk*4096 + off*8);
      }
    }

    const int kt = 2*si + g;
    if (kt <= thi){                       // wave-group-uniform
      const short* Kst = KsB + g*4608;
      const short* Vtt = VtB + g*4608;
      bf16x8 kf0[4], kf1[4];
#pragma unroll
      for (int tl = 0; tl < 4; tl++){
        kf0[tl] = *(const bf16x8*)&Kst[(tl*16 + l15)*72 + q4*8];
        kf1[tl] = *(const bf16x8*)&Kst[(tl*16 + l15)*72 + 32 + q4*8];
      }
      f16x4 vf[4][4];
#pragma unroll
      for (int nt = 0; nt < 4; nt++)
#pragma unroll
        for (int tl = 0; tl < 4; tl++)
          vf[nt][tl] = *(const f16x4*)&Vtt[(nt*16 + l15)*72 + tl*16 + q4*4];

      {
        fx4 s[4] = {};
#pragma unroll
        for (int tl = 0; tl < 4; tl++){
          s[tl] = __builtin_amdgcn_mfma_f32_16x16x32_bf16(kf0[tl], qA0, s[tl], 0,0,0);
          s[tl] = __builtin_amdgcn_mfma_f32_16x16x32_bf16(kf1[tl], qA1, s[tl], 0,0,0);
        }
        smax_pv(s, kt == thi, wl, q4, mA, lA, oA, vf);
      }
      if (kt <= tlo){
        fx4 s[4] = {};
#pragma unroll
        for (int tl = 0; tl < 4; tl++){
          s[tl] = __builtin_amdgcn_mfma_f32_16x16x32_bf16(kf0[tl], qB0, s[tl], 0,0,0);
          s[tl] = __builtin_amdgcn_mfma_f32_16x16x32_bf16(kf1[tl], qB1, s[tl], 0,0,0);
        }
        smax_pv(s, kt == tlo, wl, q4, mB, lB, oB, vf);
      }
    }
    __syncthreads();
  }

  // ---- merge group 1 into group 0 via LDS (exact, fp32) ----
  float* F = (float*)SB;                  // [wi*2+ab][lane][18]
  if (g == 1){
    float* fa = F + (((wi*2 + 0)*64 + l)*18);
#pragma unroll
    for (int nt = 0; nt < 4; nt++)
#pragma unroll
      for (int j = 0; j < 4; j++) fa[nt*4 + j] = oA[nt][j];
    fa[16] = mA; fa[17] = lA;
    float* fb = F + (((wi*2 + 1)*64 + l)*18);
#pragma unroll
    for (int nt = 0; nt < 4; nt++)
#pragma unroll
      for (int j = 0; j < 4; j++) fb[nt*4 + j] = oB[nt][j];
    fb[16] = mB; fb[17] = lB;
  }
  __syncthreads();
  if (g == 0){
    {
      const float* fa = F + (((wi*2 + 0)*64 + l)*18);
      float m1 = fa[16], l1 = fa[17];
      float mM = fmaxf(mA, m1);
      float a0 = exp2f(mA - mM), a1 = exp2f(m1 - mM);
      lA = lA*a0 + l1*a1;
#pragma unroll
      for (int nt = 0; nt < 4; nt++)
#pragma unroll
        for (int j = 0; j < 4; j++) oA[nt][j] = oA[nt][j]*a0 + fa[nt*4+j]*a1;
    }
    {
      const float* fb = F + (((wi*2 + 1)*64 + l)*18);
      float m1 = fb[16], l1 = fb[17];
      float mM = fmaxf(mB, m1);
      float a0 = exp2f(mB - mM), a1 = exp2f(m1 - mM);
      lB = lB*a0 + l1*a1;
#pragma unroll
      for (int nt = 0; nt < 4; nt++)
#pragma unroll
        for (int j = 0; j < 4; j++) oB[nt][j] = oB[nt][j]*a0 + fb[nt*4+j]*a1;
    }
    {
      float inv = 1.0f / lA;
      unsigned short* dst = ao + ((size_t)(b*SEQ + thi*64 + wl))*HID + h*64;
#pragma unroll
      for (int nt = 0; nt < 4; nt++){
        s16x4 ov;
        ov[0] = (short)f2b(oA[nt][0]*inv); ov[1] = (short)f2b(oA[nt][1]*inv);
        ov[2] = (short)f2b(oA[nt][2]*inv); ov[3] = (short)f2b(oA[nt][3]*inv);
        *(s16x4*)(dst + nt*16 + q4*4) = ov;
      }
    }
    {
      float inv = 1.0f / lB;
      unsigned short* dst = ao + ((size_t)(b*SEQ + tlo*64 + wl))*HID + h*64;
#pragma unroll
      for (int nt = 0; nt < 4; nt++){
        s16x4 ov;
        ov[0] = (short)f2b(oB[nt][0]*inv); ov[1] = (short)f2b(oB[nt][1]*inv);
        ov[2] = (short)f2b(oB[nt][2]*inv); ov[3] = (short)f2b(oB[nt][3]*inv);
        *(s16x4*)(dst + nt*16 + q4*4) = ov;
      }
    }
  }
}

// ---------------- output projection GEMM (64x128 tile, BK=128) -> fp32 ----------------
// A = attn bf16 [4096,896], B = Wo bf16 [896,896]. grid (64, 7), block 256.
__global__ __launch_bounds__(256) void out_gemm_kernel(
    const unsigned short* __restrict__ A, const unsigned short* __restrict__ Bw,
    float* __restrict__ out)
{
  __shared__ short As[64*LDA];
  __shared__ short Bs[128*LDA];
  const int tid = threadIdx.x;
  const int bm = blockIdx.x, bn = blockIdx.y;
  const int w = tid >> 6, l = tid & 63, l15 = l & 15, q4 = l >> 4;
  const int wm = w >> 1, wn = w & 1;

  fx4 acc[2][4] = {};

  const int arow = tid >> 2, acol = (tid & 3)*32;
  const int brow = tid >> 1, bcol = (tid & 1)*64;
  const unsigned short* Ag = A  + (size_t)(bm*64  + arow)*HID + acol;
  const unsigned short* Bg = Bw + (size_t)(bn*128 + brow)*HID + bcol;

  u16x8 ar[4], br[8];
#pragma unroll
  for (int p = 0; p < 4; p++) ar[p] = *(const u16x8*)(Ag + p*8);
#pragma unroll
  for (int p = 0; p < 8; p++) br[p] = *(const u16x8*)(Bg + p*8);

  for (int kt = 0; kt < 7; kt++){
#pragma unroll
    for (int p = 0; p < 4; p++) *(u16x8*)&As[arow*LDA + acol + p*8] = ar[p];
#pragma unroll
    for (int p = 0; p < 8; p++) *(u16x8*)&Bs[brow*LDA + bcol + p*8] = br[p];
    __syncthreads();
    if (kt < 6){
      const int ko_ = (kt+1)*128;
#pragma unroll
      for (int p = 0; p < 4; p++) ar[p] = *(const u16x8*)(Ag + ko_ + p*8);
#pragma unroll
      for (int p = 0; p < 8; p++) br[p] = *(const u16x8*)(Bg + ko_ + p*8);
    }
#pragma unroll
    for (int ks = 0; ks < 4; ks++){
      bf16x8 af[2], bf[4];
#pragma unroll
      for (int mt = 0; mt < 2; mt++)
        af[mt] = *(bf16x8*)&As[(wm*32 + mt*16 + l15)*LDA + ks*32 + q4*8];
#pragma unroll
      for (int nt = 0; nt < 4; nt++)
        bf[nt] = *(bf16x8*)&Bs[(wn*64 + nt*16 + l15)*LDA + ks*32 + q4*8];
#pragma unroll
      for (int mt = 0; mt < 2; mt++)
#pragma unroll
        for (int nt = 0; nt < 4; nt++)
          acc[mt][nt] = __builtin_amdgcn_mfma_f32_16x16x32_bf16(af[mt], bf[nt], acc[mt][nt], 0,0,0);
    }
    __syncthreads();
  }

#pragma unroll
  for (int mt = 0; mt < 2; mt++)
#pragma unroll
    for (int j = 0; j < 4; j++){
      int grow = bm*64 + wm*32 + mt*16 + q4*4 + j;
      float* dst = out + (size_t)grow*HID + bn*128 + wn*64;
#pragma unroll
      for (int nt = 0; nt < 4; nt++)
        dst[nt*16 + l15] = acc[mt][nt][j];
    }
}

extern "C" void kernel_launch(void* const* d_in, const int* in_sizes, int n_in,
                              void* d_out, int out_size, void* d_ws, size_t ws_size,
                              hipStream_t stream)
{
  const float* hidden = (const float*)d_in[0];
  const int*   pos    = (const int*)d_in[1];
  const float* Wq = (const float*)d_in[2]; const float* bq = (const float*)d_in[3];
  const float* Wk = (const float*)d_in[4]; const float* bk = (const float*)d_in[5];
  const float* Wv = (const float*)d_in[6]; const float* bv = (const float*)d_in[7];
  const float* Wo = (const float*)d_in[8];

  unsigned short* qws   = (unsigned short*)d_ws;                       // (B,NH,S,64) bf16 (Q pre-scaled)
  unsigned short* kws   = qws   + (size_t)BT*NH*SEQ*64;                // (B,NKV,S,64) bf16
  unsigned short* vtws  = kws   + (size_t)BT*NKV*SEQ*64;               // (B,NKV,S/64,64,64) f16
  unsigned short* wqkv  = vtws  + (size_t)BT*NKV*SEQ*64;               // (1152,896) bf16
  unsigned short* wo16  = wqkv  + (size_t)1152*HID;                    // (896,896) bf16
  unsigned short* h16   = wo16  + (size_t)HID*HID;                     // (4096,896) bf16 attn-out
  float2*         tab   = (float2*)(h16 + (size_t)NTOK*HID);           // (2048,32) rope table

  const int nwq  = HID*HID;
  const int nwkv = 2*64*HID;

  cvt_kernel<<<dim3(392, 5), 256, 0, stream>>>(
      Wq, Wk, Wv, Wo,
      wqkv, wqkv + nwq, wqkv + nwq + nwkv, wo16,
      nwq, nwkv, nwkv, nwq, tab);

  qkv_gemm_kernel<<<dim3(NTOK/64, 9), 256, 0, stream>>>(
      hidden, wqkv, bq, bk, bv, pos, tab, qws, kws, vtws);

  attn_kernel<<<dim3(16, NH, BT), 512, 0, stream>>>(qws, kws, vtws, h16);

  out_gemm_kernel<<<dim3(NTOK/64, 7), 256, 0, stream>>>(h16, wo16, (float*)d_out);
}

// Round 10
// 164.916 us; speedup vs baseline: 1.2212x; 1.2212x over previous
//
#include <hip/hip_runtime.h>

#define HID 896
#define NH 14
#define NKV 2
#define NREP 7
#define SEQ 2048
#define BT 2
#define NTOK (BT*SEQ)
#define CSCALE 0.18033688011112042f   // (1/8) * log2(e), folded into Q at projection

typedef __attribute__((ext_vector_type(8))) short bf16x8;
typedef __attribute__((ext_vector_type(8))) unsigned short u16x8;
typedef __attribute__((ext_vector_type(4))) float fx4;
typedef __attribute__((ext_vector_type(4))) short s16x4;
typedef _Float16 f16x4 __attribute__((ext_vector_type(4)));
typedef __fp16 fp16x2 __attribute__((ext_vector_type(2)));

__device__ __forceinline__ unsigned short f2b(float x){
  union { float f; unsigned u; } a; a.f = x;
  unsigned r = a.u + 0x7FFFu + ((a.u >> 16) & 1u);   // RNE
  return (unsigned short)(r >> 16);
}
__device__ __forceinline__ unsigned short f2h(float x){
  union { _Float16 h; unsigned short u; } a; a.h = (_Float16)x; return a.u;
}

// async global->LDS, 16B/lane: LDS dst = wave-uniform base + lane*16 (m97 pattern)
__device__ __forceinline__ void gll16(const unsigned short* g, short* lds){
  __builtin_amdgcn_global_load_lds(
      (const __attribute__((address_space(1))) unsigned int*)(const void*)g,
      (__attribute__((address_space(3))) unsigned int*)(void*)lds, 16, 0, 0);
}

// ------- fp32->bf16 convert (jobs 0..4: hidden + weights) + RoPE table (job 5) -------
__global__ __launch_bounds__(256) void cvt_kernel(
    const float* __restrict__ s0, const float* __restrict__ s1,
    const float* __restrict__ s2, const float* __restrict__ s3,
    const float* __restrict__ s4,
    unsigned short* __restrict__ d0, unsigned short* __restrict__ d1,
    unsigned short* __restrict__ d2, unsigned short* __restrict__ d3,
    unsigned short* __restrict__ d4,
    int c0, int c1, int c2, int c3, int c4,
    float2* __restrict__ tab)
{
  if (blockIdx.y == 5){
    for (int i = blockIdx.x*256 + threadIdx.x; i < SEQ*32; i += gridDim.x*256){
      int s = i >> 5, d = i & 31;
      float f = (float)s * exp2f(-(float)d * 0.62286151779138041f);
      float sv, cv; sincosf(f, &sv, &cv);
      tab[i] = make_float2(cv, sv);
    }
    return;
  }
  const float* s; unsigned short* d; int c;
  switch (blockIdx.y){
    case 0: s=s0; d=d0; c=c0; break;
    case 1: s=s1; d=d1; c=c1; break;
    case 2: s=s2; d=d2; c=c2; break;
    case 3: s=s3; d=d3; c=c3; break;
    default: s=s4; d=d4; c=c4; break;
  }
  for (int i = (blockIdx.x*256 + threadIdx.x)*8; i < c; i += gridDim.x*2048){
    float4 a = *(const float4*)(s + i);
    float4 b = *(const float4*)(s + i + 4);
    u16x8 o;
    o[0]=f2b(a.x); o[1]=f2b(a.y); o[2]=f2b(a.z); o[3]=f2b(a.w);
    o[4]=f2b(b.x); o[5]=f2b(b.y); o[6]=f2b(b.z); o[7]=f2b(b.w);
    *(u16x8*)(d + i) = o;
  }
}

// ---------------- QKV projection GEMM (64x128, BK=64, global_load_lds + XOR swizzle) ----------------
// A = hidden bf16 [4096,896], B = WQKV bf16 [1152,896]. grid (64,9), block 256 (2x2 waves).
// LDS unpadded [rows][64]; block cb of row r holds global block cb^(r&7) (bank-spread, no pad).
__global__ __launch_bounds__(256) void qkv_gemm_kernel(
    const unsigned short* __restrict__ A, const unsigned short* __restrict__ Bw,
    const float* __restrict__ bq, const float* __restrict__ bk, const float* __restrict__ bv,
    const int* __restrict__ pos, const float2* __restrict__ tab,
    unsigned short* __restrict__ qo, unsigned short* __restrict__ ko,
    unsigned short* __restrict__ vt)
{
  __shared__ short As[64*64];     // 8 KB
  __shared__ short Bs[128*64];    // 16 KB
  const int tid = threadIdx.x;
  const int bm = blockIdx.x, bn = blockIdx.y;
  const int w = tid >> 6, l = tid & 63, l15 = l & 15, q4 = l >> 4;
  const int wm = w >> 1, wn = w & 1;
  const int lr = l >> 3;                 // row-in-chunk 0..7
  const int cbg = (l & 7) ^ lr;          // swizzled global 16B-block
  const int sw = l15 & 7;                // frag-read swizzle key

  fx4 acc[2][4] = {};

  const unsigned short* Ag = A  + (size_t)(bm*64)*HID;
  const unsigned short* Bg = Bw + (size_t)(bn*128)*HID;

  for (int kt = 0; kt < 14; kt++){
    const int kc = kt*64 + cbg*8;
    // A: 8 chunks (1 KB each), 2 per wave; B: 16 chunks, 4 per wave
#pragma unroll
    for (int p = 0; p < 2; p++){
      int c = p*4 + w;
      gll16(Ag + (size_t)(c*8 + lr)*HID + kc, &As[c*512]);
    }
#pragma unroll
    for (int p = 0; p < 4; p++){
      int c = p*4 + w;
      gll16(Bg + (size_t)(c*8 + lr)*HID + kc, &Bs[c*512]);
    }
    __syncthreads();                     // drains vmcnt -> LDS valid
#pragma unroll
    for (int ks = 0; ks < 2; ks++){
      bf16x8 af[2], bf[4];
#pragma unroll
      for (int mt = 0; mt < 2; mt++){
        int r = wm*32 + mt*16 + l15;
        af[mt] = *(bf16x8*)&As[r*64 + ((ks*4 + q4) ^ sw)*8];
      }
#pragma unroll
      for (int nt = 0; nt < 4; nt++){
        int r = wn*64 + nt*16 + l15;
        bf[nt] = *(bf16x8*)&Bs[r*64 + ((ks*4 + q4) ^ sw)*8];
      }
#pragma unroll
      for (int mt = 0; mt < 2; mt++)
#pragma unroll
        for (int nt = 0; nt < 4; nt++)
          acc[mt][nt] = __builtin_amdgcn_mfma_f32_16x16x32_bf16(af[mt], bf[nt], acc[mt][nt], 0,0,0);
    }
    __syncthreads();                     // protect LDS before next stage
  }

  const int hu = bn*2 + wn;
  const float* bias; int kind, hloc;
  if (hu < NH)      { bias = bq + hu*64;      kind = 0; hloc = hu; }
  else if (hu < 16) { bias = bk + (hu-NH)*64; kind = 1; hloc = hu-NH; }
  else              { bias = bv + (hu-16)*64; kind = 2; hloc = hu-16; }
  float bl[4];
#pragma unroll
  for (int nt = 0; nt < 4; nt++) bl[nt] = bias[nt*16 + l15];

  if (kind == 2){
#pragma unroll
    for (int mt = 0; mt < 2; mt++)
#pragma unroll
      for (int j = 0; j < 4; j++){
        int grow = bm*64 + wm*32 + mt*16 + q4*4 + j;
        int b = grow >> 11, s = grow & (SEQ-1);
        int tile = s >> 6, key = s & 63;
        unsigned short* dst = vt + (size_t)(((b*NKV + hloc)*(SEQ/64) + tile)*4096);
#pragma unroll
        for (int nt = 0; nt < 4; nt++)
          dst[(nt*16 + l15)*64 + key] = f2h(acc[mt][nt][j] + bl[nt]);
      }
  } else {
    const float qs = (kind == 0) ? CSCALE : 1.0f;
#pragma unroll
    for (int mt = 0; mt < 2; mt++)
#pragma unroll
      for (int j = 0; j < 4; j++){
        int grow = bm*64 + wm*32 + mt*16 + q4*4 + j;
        int b = grow >> 11, s = grow & (SEQ-1);
        int p = pos[grow];
        const float2* rp = tab + p*32 + l15;
        float2 cs0 = rp[0], cs1 = rp[16];
        unsigned short* dst = (kind == 0)
            ? qo + ((size_t)(b*NH  + hloc)*SEQ + s)*64
            : ko + ((size_t)(b*NKV + hloc)*SEQ + s)*64;
        float x1 = acc[mt][0][j] + bl[0], x2 = acc[mt][2][j] + bl[2];
        float y1 = acc[mt][1][j] + bl[1], y2 = acc[mt][3][j] + bl[3];
        dst[l15]      = f2b((x1*cs0.x - x2*cs0.y)*qs);
        dst[16 + l15] = f2b((y1*cs1.x - y2*cs1.y)*qs);
        dst[32 + l15] = f2b((x2*cs0.x + x1*cs0.y)*qs);
        dst[48 + l15] = f2b((y2*cs1.x + y1*cs1.y)*qs);
      }
  }
}

// -------- per-tile softmax + PV update (S^T orientation; CSCALE pre-folded into Q) --------
__device__ __forceinline__ void smax_pv(
    const fx4* s, bool diag, int wl, int q4,
    float& m_run, float& l_run, fx4* o, const f16x4 vf[4][4])
{
  float tv[16];
#pragma unroll
  for (int tl = 0; tl < 4; tl++)
#pragma unroll
    for (int j = 0; j < 4; j++){
      float x = s[tl][j];
      if (diag && (tl*16 + q4*4 + j > wl)) x = -1e30f;
      tv[tl*4+j] = x;
    }
  float mx = tv[0];
#pragma unroll
  for (int i = 1; i < 16; i++) mx = fmaxf(mx, tv[i]);
  mx = fmaxf(mx, __shfl_xor(mx, 16));
  mx = fmaxf(mx, __shfl_xor(mx, 32));
  float mn = fmaxf(m_run, mx);
  float al = exp2f(m_run - mn);
  m_run = mn;
  float p[16], rs = 0.f;
#pragma unroll
  for (int i = 0; i < 16; i++){ p[i] = exp2f(tv[i] - mn); rs += p[i]; }
  rs += __shfl_xor(rs, 16);
  rs += __shfl_xor(rs, 32);
  l_run = l_run*al + rs;
#pragma unroll
  for (int nt = 0; nt < 4; nt++)
#pragma unroll
    for (int j = 0; j < 4; j++) o[nt][j] *= al;
  f16x4 pf[4];
#pragma unroll
  for (int tl = 0; tl < 4; tl++){
    union { f16x4 v; fp16x2 h[2]; } u;
    u.h[0] = __builtin_amdgcn_cvt_pkrtz(p[tl*4+0], p[tl*4+1]);
    u.h[1] = __builtin_amdgcn_cvt_pkrtz(p[tl*4+2], p[tl*4+3]);
    pf[tl] = u.v;
  }
#pragma unroll
  for (int nt = 0; nt < 4; nt++)
#pragma unroll
    for (int tl = 0; tl < 4; tl++)
      o[nt] = __builtin_amdgcn_mfma_f32_16x16x16f16(vf[nt][tl], pf[tl], o[nt], 0,0,0);
}

// ---------------- flash attention (R7 paired + split-K; best measured 59.4us) ----------------
__global__ __launch_bounds__(512) void attn_kernel(
    const unsigned short* __restrict__ q, const unsigned short* __restrict__ k,
    const unsigned short* __restrict__ vt, unsigned short* __restrict__ ao)
{
  __shared__ short SB[4*64*72];
  short* KsB = SB;
  short* VtB = SB + 2*64*72;

  const int tid = threadIdx.x;
  const int w = tid >> 6, l = tid & 63, l15 = l & 15, q4 = l >> 4;
  const int g = w >> 2, wi = w & 3;
  const int tlo = blockIdx.x, thi = 31 - tlo;
  const int h = blockIdx.y, b = blockIdx.z, kvh = h / NREP;
  const int wl = wi*16 + l15;

  const unsigned short* qbase = q + ((size_t)(b*NH + h)*SEQ)*64;
  const unsigned short* qpA = qbase + (size_t)(thi*64 + wl)*64;
  const unsigned short* qpB = qbase + (size_t)(tlo*64 + wl)*64;
  bf16x8 qA0 = *(const bf16x8*)(qpA + q4*8), qA1 = *(const bf16x8*)(qpA + 32 + q4*8);
  bf16x8 qB0 = *(const bf16x8*)(qpB + q4*8), qB1 = *(const bf16x8*)(qpB + 32 + q4*8);

  fx4 oA[4] = {}, oB[4] = {};
  float mA = -1e30f, lA = 0.f, mB = -1e30f, lB = 0.f;

  const unsigned short* kbase = k  + ((size_t)(b*NKV + kvh)*SEQ)*64;
  const unsigned short* vbase = vt + (size_t)((b*NKV + kvh)*(SEQ/64))*4096;

  const int P = (thi + 2) >> 1;

  u16x8 kreg[2], vreg[2];
#pragma unroll
  for (int p = 0; p < 2; p++){
    int idx = p*512 + tid, tile = idx >> 9, off = idx & 511;
    kreg[p] = *(const u16x8*)(kbase + (size_t)tile*4096 + off*8);
    vreg[p] = *(const u16x8*)(vbase + (size_t)tile*4096 + off*8);
  }

  for (int si = 0; si < P; si++){
#pragma unroll
    for (int p = 0; p < 2; p++){
      int idx = p*512 + tid, tile = idx >> 9, off = idx & 511;
      int rr = off >> 3, g8 = off & 7;
      *(u16x8*)&KsB[tile*4608 + rr*72 + g8*8] = kreg[p];
      *(u16x8*)&VtB[tile*4608 + rr*72 + g8*8] = vreg[p];
    }
    __syncthreads();

    if (si + 1 < P){
      const int k0n = 2*(si+1);
#pragma unroll
      for (int p = 0; p < 2; p++){
        int idx = p*512 + tid, tile = idx >> 9, off = idx & 511;
        int tk = k0n + tile; if (tk > thi) tk = thi;
        kreg[p] = *(const u16x8*)(kbase + (size_t)tk*4096 + off*8);
        vreg[p] = *(const u16x8*)(vbase + (size_t)tk*4096 + off*8);
      }
    }

    const int kt = 2*si + g;
    if (kt <= thi){
      const short* Kst = KsB + g*4608;
      const short* Vtt = VtB + g*4608;
      bf16x8 kf0[4], kf1[4];
#pragma unroll
      for (int tl = 0; tl < 4; tl++){
        kf0[tl] = *(const bf16x8*)&Kst[(tl*16 + l15)*72 + q4*8];
        kf1[tl] = *(const bf16x8*)&Kst[(tl*16 + l15)*72 + 32 + q4*8];
      }
      f16x4 vf[4][4];
#pragma unroll
      for (int nt = 0; nt < 4; nt++)
#pragma unroll
        for (int tl = 0; tl < 4; tl++)
          vf[nt][tl] = *(const f16x4*)&Vtt[(nt*16 + l15)*72 + tl*16 + q4*4];

      {
        fx4 s[4] = {};
#pragma unroll
        for (int tl = 0; tl < 4; tl++){
          s[tl] = __builtin_amdgcn_mfma_f32_16x16x32_bf16(kf0[tl], qA0, s[tl], 0,0,0);
          s[tl] = __builtin_amdgcn_mfma_f32_16x16x32_bf16(kf1[tl], qA1, s[tl], 0,0,0);
        }
        smax_pv(s, kt == thi, wl, q4, mA, lA, oA, vf);
      }
      if (kt <= tlo){
        fx4 s[4] = {};
#pragma unroll
        for (int tl = 0; tl < 4; tl++){
          s[tl] = __builtin_amdgcn_mfma_f32_16x16x32_bf16(kf0[tl], qB0, s[tl], 0,0,0);
          s[tl] = __builtin_amdgcn_mfma_f32_16x16x32_bf16(kf1[tl], qB1, s[tl], 0,0,0);
        }
        smax_pv(s, kt == tlo, wl, q4, mB, lB, oB, vf);
      }
    }
    __syncthreads();
  }

  float* F = (float*)SB;
  if (g == 1){
    float* fa = F + (((wi*2 + 0)*64 + l)*18);
#pragma unroll
    for (int nt = 0; nt < 4; nt++)
#pragma unroll
      for (int j = 0; j < 4; j++) fa[nt*4 + j] = oA[nt][j];
    fa[16] = mA; fa[17] = lA;
    float* fb = F + (((wi*2 + 1)*64 + l)*18);
#pragma unroll
    for (int nt = 0; nt < 4; nt++)
#pragma unroll
      for (int j = 0; j < 4; j++) fb[nt*4 + j] = oB[nt][j];
    fb[16] = mB; fb[17] = lB;
  }
  __syncthreads();
  if (g == 0){
    {
      const float* fa = F + (((wi*2 + 0)*64 + l)*18);
      float m1 = fa[16], l1 = fa[17];
      float mM = fmaxf(mA, m1);
      float a0 = exp2f(mA - mM), a1 = exp2f(m1 - mM);
      lA = lA*a0 + l1*a1;
#pragma unroll
      for (int nt = 0; nt < 4; nt++)
#pragma unroll
        for (int j = 0; j < 4; j++) oA[nt][j] = oA[nt][j]*a0 + fa[nt*4+j]*a1;
    }
    {
      const float* fb = F + (((wi*2 + 1)*64 + l)*18);
      float m1 = fb[16], l1 = fb[17];
      float mM = fmaxf(mB, m1);
      float a0 = exp2f(mB - mM), a1 = exp2f(m1 - mM);
      lB = lB*a0 + l1*a1;
#pragma unroll
      for (int nt = 0; nt < 4; nt++)
#pragma unroll
        for (int j = 0; j < 4; j++) oB[nt][j] = oB[nt][j]*a0 + fb[nt*4+j]*a1;
    }
    {
      float inv = 1.0f / lA;
      unsigned short* dst = ao + ((size_t)(b*SEQ + thi*64 + wl))*HID + h*64;
#pragma unroll
      for (int nt = 0; nt < 4; nt++){
        s16x4 ov;
        ov[0] = (short)f2b(oA[nt][0]*inv); ov[1] = (short)f2b(oA[nt][1]*inv);
        ov[2] = (short)f2b(oA[nt][2]*inv); ov[3] = (short)f2b(oA[nt][3]*inv);
        *(s16x4*)(dst + nt*16 + q4*4) = ov;
      }
    }
    {
      float inv = 1.0f / lB;
      unsigned short* dst = ao + ((size_t)(b*SEQ + tlo*64 + wl))*HID + h*64;
#pragma unroll
      for (int nt = 0; nt < 4; nt++){
        s16x4 ov;
        ov[0] = (short)f2b(oB[nt][0]*inv); ov[1] = (short)f2b(oB[nt][1]*inv);
        ov[2] = (short)f2b(oB[nt][2]*inv); ov[3] = (short)f2b(oB[nt][3]*inv);
        *(s16x4*)(dst + nt*16 + q4*4) = ov;
      }
    }
  }
}

// ---------------- output projection GEMM (64x128, BK=64, global_load_lds + swizzle) ----------------
// A = attn bf16 [4096,896], B = Wo bf16 [896,896]. grid (64, 7), block 256.
__global__ __launch_bounds__(256) void out_gemm_kernel(
    const unsigned short* __restrict__ A, const unsigned short* __restrict__ Bw,
    float* __restrict__ out)
{
  __shared__ short As[64*64];
  __shared__ short Bs[128*64];
  const int tid = threadIdx.x;
  const int bm = blockIdx.x, bn = blockIdx.y;
  const int w = tid >> 6, l = tid & 63, l15 = l & 15, q4 = l >> 4;
  const int wm = w >> 1, wn = w & 1;
  const int lr = l >> 3;
  const int cbg = (l & 7) ^ lr;
  const int sw = l15 & 7;

  fx4 acc[2][4] = {};

  const unsigned short* Ag = A  + (size_t)(bm*64)*HID;
  const unsigned short* Bg = Bw + (size_t)(bn*128)*HID;

  for (int kt = 0; kt < 14; kt++){
    const int kc = kt*64 + cbg*8;
#pragma unroll
    for (int p = 0; p < 2; p++){
      int c = p*4 + w;
      gll16(Ag + (size_t)(c*8 + lr)*HID + kc, &As[c*512]);
    }
#pragma unroll
    for (int p = 0; p < 4; p++){
      int c = p*4 + w;
      gll16(Bg + (size_t)(c*8 + lr)*HID + kc, &Bs[c*512]);
    }
    __syncthreads();
#pragma unroll
    for (int ks = 0; ks < 2; ks++){
      bf16x8 af[2], bf[4];
#pragma unroll
      for (int mt = 0; mt < 2; mt++){
        int r = wm*32 + mt*16 + l15;
        af[mt] = *(bf16x8*)&As[r*64 + ((ks*4 + q4) ^ sw)*8];
      }
#pragma unroll
      for (int nt = 0; nt < 4; nt++){
        int r = wn*64 + nt*16 + l15;
        bf[nt] = *(bf16x8*)&Bs[r*64 + ((ks*4 + q4) ^ sw)*8];
      }
#pragma unroll
      for (int mt = 0; mt < 2; mt++)
#pragma unroll
        for (int nt = 0; nt < 4; nt++)
          acc[mt][nt] = __builtin_amdgcn_mfma_f32_16x16x32_bf16(af[mt], bf[nt], acc[mt][nt], 0,0,0);
    }
    __syncthreads();
  }

#pragma unroll
  for (int mt = 0; mt < 2; mt++)
#pragma unroll
    for (int j = 0; j < 4; j++){
      int grow = bm*64 + wm*32 + mt*16 + q4*4 + j;
      float* dst = out + (size_t)grow*HID + bn*128 + wn*64;
#pragma unroll
      for (int nt = 0; nt < 4; nt++)
        dst[nt*16 + l15] = acc[mt][nt][j];
    }
}

extern "C" void kernel_launch(void* const* d_in, const int* in_sizes, int n_in,
                              void* d_out, int out_size, void* d_ws, size_t ws_size,
                              hipStream_t stream)
{
  const float* hidden = (const float*)d_in[0];
  const int*   pos    = (const int*)d_in[1];
  const float* Wq = (const float*)d_in[2]; const float* bq = (const float*)d_in[3];
  const float* Wk = (const float*)d_in[4]; const float* bk = (const float*)d_in[5];
  const float* Wv = (const float*)d_in[6]; const float* bv = (const float*)d_in[7];
  const float* Wo = (const float*)d_in[8];

  unsigned short* qws   = (unsigned short*)d_ws;                       // (B,NH,S,64) bf16 (Q pre-scaled)
  unsigned short* kws   = qws   + (size_t)BT*NH*SEQ*64;                // (B,NKV,S,64) bf16
  unsigned short* vtws  = kws   + (size_t)BT*NKV*SEQ*64;               // (B,NKV,S/64,64,64) f16
  unsigned short* wqkv  = vtws  + (size_t)BT*NKV*SEQ*64;               // (1152,896) bf16
  unsigned short* wo16  = wqkv  + (size_t)1152*HID;                    // (896,896) bf16
  unsigned short* h16   = wo16  + (size_t)HID*HID;                     // (4096,896) bf16: hidden, then attn-out
  float2*         tab   = (float2*)(h16 + (size_t)NTOK*HID);           // (2048,32) rope table

  const int nh   = NTOK*HID;
  const int nwq  = HID*HID;
  const int nwkv = 2*64*HID;

  cvt_kernel<<<dim3(448, 6), 256, 0, stream>>>(
      hidden, Wq, Wk, Wv, Wo,
      h16, wqkv, wqkv + nwq, wqkv + nwq + nwkv, wo16,
      nh, nwq, nwkv, nwkv, nwq, tab);

  qkv_gemm_kernel<<<dim3(NTOK/64, 9), 256, 0, stream>>>(
      h16, wqkv, bq, bk, bv, pos, tab, qws, kws, vtws);

  attn_kernel<<<dim3(16, NH, BT), 512, 0, stream>>>(qws, kws, vtws, h16);

  out_gemm_kernel<<<dim3(NTOK/64, 7), 256, 0, stream>>>(h16, wo16, (float*)d_out);
}

// Round 11
// 163.126 us; speedup vs baseline: 1.2346x; 1.0110x over previous
//
#include <hip/hip_runtime.h>

#define HID 896
#define NH 14
#define NKV 2
#define NREP 7
#define SEQ 2048
#define BT 2
#define NTOK (BT*SEQ)
#define CSCALE 0.18033688011112042f   // (1/8) * log2(e), folded into Q at projection

typedef __attribute__((ext_vector_type(8))) short bf16x8;
typedef __attribute__((ext_vector_type(8))) unsigned short u16x8;
typedef __attribute__((ext_vector_type(4))) float fx4;
typedef __attribute__((ext_vector_type(4))) short s16x4;
typedef _Float16 f16x4 __attribute__((ext_vector_type(4)));
typedef __fp16 fp16x2 __attribute__((ext_vector_type(2)));

__device__ __forceinline__ unsigned short f2b(float x){
  union { float f; unsigned u; } a; a.f = x;
  unsigned r = a.u + 0x7FFFu + ((a.u >> 16) & 1u);   // RNE
  return (unsigned short)(r >> 16);
}
__device__ __forceinline__ unsigned short f2h(float x){
  union { _Float16 h; unsigned short u; } a; a.h = (_Float16)x; return a.u;
}

// async global->LDS, 16B/lane: LDS dst = wave-uniform base + lane*16 (m97 pattern)
__device__ __forceinline__ void gll16(const unsigned short* g, short* lds){
  __builtin_amdgcn_global_load_lds(
      (const __attribute__((address_space(1))) unsigned int*)(const void*)g,
      (__attribute__((address_space(3))) unsigned int*)(void*)lds, 16, 0, 0);
}

// ------- fp32->bf16 convert (jobs 0..4: hidden + weights) + RoPE table (job 5) -------
__global__ __launch_bounds__(256) void cvt_kernel(
    const float* __restrict__ s0, const float* __restrict__ s1,
    const float* __restrict__ s2, const float* __restrict__ s3,
    const float* __restrict__ s4,
    unsigned short* __restrict__ d0, unsigned short* __restrict__ d1,
    unsigned short* __restrict__ d2, unsigned short* __restrict__ d3,
    unsigned short* __restrict__ d4,
    int c0, int c1, int c2, int c3, int c4,
    float2* __restrict__ tab)
{
  if (blockIdx.y == 5){
    for (int i = blockIdx.x*256 + threadIdx.x; i < SEQ*32; i += gridDim.x*256){
      int s = i >> 5, d = i & 31;
      float f = (float)s * exp2f(-(float)d * 0.62286151779138041f);
      float sv, cv; sincosf(f, &sv, &cv);
      tab[i] = make_float2(cv, sv);
    }
    return;
  }
  const float* s; unsigned short* d; int c;
  switch (blockIdx.y){
    case 0: s=s0; d=d0; c=c0; break;
    case 1: s=s1; d=d1; c=c1; break;
    case 2: s=s2; d=d2; c=c2; break;
    case 3: s=s3; d=d3; c=c3; break;
    default: s=s4; d=d4; c=c4; break;
  }
  for (int i = (blockIdx.x*256 + threadIdx.x)*8; i < c; i += gridDim.x*2048){
    float4 a = *(const float4*)(s + i);
    float4 b = *(const float4*)(s + i + 4);
    u16x8 o;
    o[0]=f2b(a.x); o[1]=f2b(a.y); o[2]=f2b(a.z); o[3]=f2b(a.w);
    o[4]=f2b(b.x); o[5]=f2b(b.y); o[6]=f2b(b.z); o[7]=f2b(b.w);
    *(u16x8*)(d + i) = o;
  }
}

// ---------------- QKV projection GEMM: dbuf gll16 pipeline + XOR swizzle ----------------
// A = hidden bf16 [4096,896], B = WQKV bf16 [1152,896]. grid (64,9), block 256 (2x2 waves).
// Prefetch tile k+1 issued BEFORE tile k's barrier; s_waitcnt vmcnt(6) keeps it in flight.
__global__ __launch_bounds__(256) void qkv_gemm_kernel(
    const unsigned short* __restrict__ A, const unsigned short* __restrict__ Bw,
    const float* __restrict__ bq, const float* __restrict__ bk, const float* __restrict__ bv,
    const int* __restrict__ pos, const float2* __restrict__ tab,
    unsigned short* __restrict__ qo, unsigned short* __restrict__ ko,
    unsigned short* __restrict__ vt)
{
  __shared__ short As[2][64*64];     // 16 KB
  __shared__ short Bs[2][128*64];    // 32 KB
  const int tid = threadIdx.x;
  const int bm = blockIdx.x, bn = blockIdx.y;
  const int w = tid >> 6, l = tid & 63, l15 = l & 15, q4 = l >> 4;
  const int wm = w >> 1, wn = w & 1;
  const int lr = l >> 3;                 // row-in-chunk 0..7
  const int cbg = (l & 7) ^ lr;          // swizzled global 16B-block
  const int sw = l15 & 7;                // frag-read swizzle key

  fx4 acc[2][4] = {};

  const unsigned short* Ag = A  + (size_t)(bm*64)*HID;
  const unsigned short* Bg = Bw + (size_t)(bn*128)*HID;

  auto issue = [&](int kt, int buf){
    const int kc = kt*64 + cbg*8;
#pragma unroll
    for (int p = 0; p < 2; p++){
      int c = p*4 + w;
      gll16(Ag + (size_t)(c*8 + lr)*HID + kc, &As[buf][c*512]);
    }
#pragma unroll
    for (int p = 0; p < 4; p++){
      int c = p*4 + w;
      gll16(Bg + (size_t)(c*8 + lr)*HID + kc, &Bs[buf][c*512]);
    }
  };

  issue(0, 0);
  for (int kt = 0; kt < 14; kt++){
    const int cur = kt & 1;
    if (kt < 13){
      issue(kt+1, cur^1);                                    // 6 more in flight
      asm volatile("s_waitcnt vmcnt(6)\n\ts_barrier" ::: "memory");  // cur landed; next stays out
    } else {
      asm volatile("s_waitcnt vmcnt(0)\n\ts_barrier" ::: "memory");
    }
#pragma unroll
    for (int ks = 0; ks < 2; ks++){
      bf16x8 af[2], bf[4];
#pragma unroll
      for (int mt = 0; mt < 2; mt++){
        int r = wm*32 + mt*16 + l15;
        af[mt] = *(bf16x8*)&As[cur][r*64 + ((ks*4 + q4) ^ sw)*8];
      }
#pragma unroll
      for (int nt = 0; nt < 4; nt++){
        int r = wn*64 + nt*16 + l15;
        bf[nt] = *(bf16x8*)&Bs[cur][r*64 + ((ks*4 + q4) ^ sw)*8];
      }
#pragma unroll
      for (int mt = 0; mt < 2; mt++)
#pragma unroll
        for (int nt = 0; nt < 4; nt++)
          acc[mt][nt] = __builtin_amdgcn_mfma_f32_16x16x32_bf16(af[mt], bf[nt], acc[mt][nt], 0,0,0);
    }
    asm volatile("s_barrier" ::: "memory");                  // buf[cur] free for kt+2 issue
  }

  const int hu = bn*2 + wn;
  const float* bias; int kind, hloc;
  if (hu < NH)      { bias = bq + hu*64;      kind = 0; hloc = hu; }
  else if (hu < 16) { bias = bk + (hu-NH)*64; kind = 1; hloc = hu-NH; }
  else              { bias = bv + (hu-16)*64; kind = 2; hloc = hu-16; }
  float bl[4];
#pragma unroll
  for (int nt = 0; nt < 4; nt++) bl[nt] = bias[nt*16 + l15];

  if (kind == 2){
#pragma unroll
    for (int mt = 0; mt < 2; mt++)
#pragma unroll
      for (int j = 0; j < 4; j++){
        int grow = bm*64 + wm*32 + mt*16 + q4*4 + j;
        int b = grow >> 11, s = grow & (SEQ-1);
        int tile = s >> 6, key = s & 63;
        unsigned short* dst = vt + (size_t)(((b*NKV + hloc)*(SEQ/64) + tile)*4096);
#pragma unroll
        for (int nt = 0; nt < 4; nt++)
          dst[(nt*16 + l15)*64 + key] = f2h(acc[mt][nt][j] + bl[nt]);
      }
  } else {
    const float qs = (kind == 0) ? CSCALE : 1.0f;
#pragma unroll
    for (int mt = 0; mt < 2; mt++)
#pragma unroll
      for (int j = 0; j < 4; j++){
        int grow = bm*64 + wm*32 + mt*16 + q4*4 + j;
        int b = grow >> 11, s = grow & (SEQ-1);
        int p = pos[grow];
        const float2* rp = tab + p*32 + l15;
        float2 cs0 = rp[0], cs1 = rp[16];
        unsigned short* dst = (kind == 0)
            ? qo + ((size_t)(b*NH  + hloc)*SEQ + s)*64
            : ko + ((size_t)(b*NKV + hloc)*SEQ + s)*64;
        float x1 = acc[mt][0][j] + bl[0], x2 = acc[mt][2][j] + bl[2];
        float y1 = acc[mt][1][j] + bl[1], y2 = acc[mt][3][j] + bl[3];
        dst[l15]      = f2b((x1*cs0.x - x2*cs0.y)*qs);
        dst[16 + l15] = f2b((y1*cs1.x - y2*cs1.y)*qs);
        dst[32 + l15] = f2b((x2*cs0.x + x1*cs0.y)*qs);
        dst[48 + l15] = f2b((y2*cs1.x + y1*cs1.y)*qs);
      }
  }
}

// -------- per-tile softmax + PV update (S^T orientation; CSCALE pre-folded into Q) --------
__device__ __forceinline__ void smax_pv(
    const fx4* s, bool diag, int wl, int q4,
    float& m_run, float& l_run, fx4* o, const f16x4 vf[4][4])
{
  float tv[16];
#pragma unroll
  for (int tl = 0; tl < 4; tl++)
#pragma unroll
    for (int j = 0; j < 4; j++){
      float x = s[tl][j];
      if (diag && (tl*16 + q4*4 + j > wl)) x = -1e30f;
      tv[tl*4+j] = x;
    }
  float mx = tv[0];
#pragma unroll
  for (int i = 1; i < 16; i++) mx = fmaxf(mx, tv[i]);
  mx = fmaxf(mx, __shfl_xor(mx, 16));
  mx = fmaxf(mx, __shfl_xor(mx, 32));
  float mn = fmaxf(m_run, mx);
  float al = exp2f(m_run - mn);
  m_run = mn;
  float p[16], rs = 0.f;
#pragma unroll
  for (int i = 0; i < 16; i++){ p[i] = exp2f(tv[i] - mn); rs += p[i]; }
  rs += __shfl_xor(rs, 16);
  rs += __shfl_xor(rs, 32);
  l_run = l_run*al + rs;
#pragma unroll
  for (int nt = 0; nt < 4; nt++)
#pragma unroll
    for (int j = 0; j < 4; j++) o[nt][j] *= al;
  f16x4 pf[4];
#pragma unroll
  for (int tl = 0; tl < 4; tl++){
    union { f16x4 v; fp16x2 h[2]; } u;
    u.h[0] = __builtin_amdgcn_cvt_pkrtz(p[tl*4+0], p[tl*4+1]);
    u.h[1] = __builtin_amdgcn_cvt_pkrtz(p[tl*4+2], p[tl*4+3]);
    pf[tl] = u.v;
  }
#pragma unroll
  for (int nt = 0; nt < 4; nt++)
#pragma unroll
    for (int tl = 0; tl < 4; tl++)
      o[nt] = __builtin_amdgcn_mfma_f32_16x16x16f16(vf[nt][tl], pf[tl], o[nt], 0,0,0);
}

// ---------------- flash attention (R7 paired + split-K; best measured 59.4us) ----------------
__global__ __launch_bounds__(512) void attn_kernel(
    const unsigned short* __restrict__ q, const unsigned short* __restrict__ k,
    const unsigned short* __restrict__ vt, unsigned short* __restrict__ ao)
{
  __shared__ short SB[4*64*72];
  short* KsB = SB;
  short* VtB = SB + 2*64*72;

  const int tid = threadIdx.x;
  const int w = tid >> 6, l = tid & 63, l15 = l & 15, q4 = l >> 4;
  const int g = w >> 2, wi = w & 3;
  const int tlo = blockIdx.x, thi = 31 - tlo;
  const int h = blockIdx.y, b = blockIdx.z, kvh = h / NREP;
  const int wl = wi*16 + l15;

  const unsigned short* qbase = q + ((size_t)(b*NH + h)*SEQ)*64;
  const unsigned short* qpA = qbase + (size_t)(thi*64 + wl)*64;
  const unsigned short* qpB = qbase + (size_t)(tlo*64 + wl)*64;
  bf16x8 qA0 = *(const bf16x8*)(qpA + q4*8), qA1 = *(const bf16x8*)(qpA + 32 + q4*8);
  bf16x8 qB0 = *(const bf16x8*)(qpB + q4*8), qB1 = *(const bf16x8*)(qpB + 32 + q4*8);

  fx4 oA[4] = {}, oB[4] = {};
  float mA = -1e30f, lA = 0.f, mB = -1e30f, lB = 0.f;

  const unsigned short* kbase = k  + ((size_t)(b*NKV + kvh)*SEQ)*64;
  const unsigned short* vbase = vt + (size_t)((b*NKV + kvh)*(SEQ/64))*4096;

  const int P = (thi + 2) >> 1;

  u16x8 kreg[2], vreg[2];
#pragma unroll
  for (int p = 0; p < 2; p++){
    int idx = p*512 + tid, tile = idx >> 9, off = idx & 511;
    kreg[p] = *(const u16x8*)(kbase + (size_t)tile*4096 + off*8);
    vreg[p] = *(const u16x8*)(vbase + (size_t)tile*4096 + off*8);
  }

  for (int si = 0; si < P; si++){
#pragma unroll
    for (int p = 0; p < 2; p++){
      int idx = p*512 + tid, tile = idx >> 9, off = idx & 511;
      int rr = off >> 3, g8 = off & 7;
      *(u16x8*)&KsB[tile*4608 + rr*72 + g8*8] = kreg[p];
      *(u16x8*)&VtB[tile*4608 + rr*72 + g8*8] = vreg[p];
    }
    __syncthreads();

    if (si + 1 < P){
      const int k0n = 2*(si+1);
#pragma unroll
      for (int p = 0; p < 2; p++){
        int idx = p*512 + tid, tile = idx >> 9, off = idx & 511;
        int tk = k0n + tile; if (tk > thi) tk = thi;
        kreg[p] = *(const u16x8*)(kbase + (size_t)tk*4096 + off*8);
        vreg[p] = *(const u16x8*)(vbase + (size_t)tk*4096 + off*8);
      }
    }

    const int kt = 2*si + g;
    if (kt <= thi){
      const short* Kst = KsB + g*4608;
      const short* Vtt = VtB + g*4608;
      bf16x8 kf0[4], kf1[4];
#pragma unroll
      for (int tl = 0; tl < 4; tl++){
        kf0[tl] = *(const bf16x8*)&Kst[(tl*16 + l15)*72 + q4*8];
        kf1[tl] = *(const bf16x8*)&Kst[(tl*16 + l15)*72 + 32 + q4*8];
      }
      f16x4 vf[4][4];
#pragma unroll
      for (int nt = 0; nt < 4; nt++)
#pragma unroll
        for (int tl = 0; tl < 4; tl++)
          vf[nt][tl] = *(const f16x4*)&Vtt[(nt*16 + l15)*72 + tl*16 + q4*4];

      {
        fx4 s[4] = {};
#pragma unroll
        for (int tl = 0; tl < 4; tl++){
          s[tl] = __builtin_amdgcn_mfma_f32_16x16x32_bf16(kf0[tl], qA0, s[tl], 0,0,0);
          s[tl] = __builtin_amdgcn_mfma_f32_16x16x32_bf16(kf1[tl], qA1, s[tl], 0,0,0);
        }
        smax_pv(s, kt == thi, wl, q4, mA, lA, oA, vf);
      }
      if (kt <= tlo){
        fx4 s[4] = {};
#pragma unroll
        for (int tl = 0; tl < 4; tl++){
          s[tl] = __builtin_amdgcn_mfma_f32_16x16x32_bf16(kf0[tl], qB0, s[tl], 0,0,0);
          s[tl] = __builtin_amdgcn_mfma_f32_16x16x32_bf16(kf1[tl], qB1, s[tl], 0,0,0);
        }
        smax_pv(s, kt == tlo, wl, q4, mB, lB, oB, vf);
      }
    }
    __syncthreads();
  }

  float* F = (float*)SB;
  if (g == 1){
    float* fa = F + (((wi*2 + 0)*64 + l)*18);
#pragma unroll
    for (int nt = 0; nt < 4; nt++)
#pragma unroll
      for (int j = 0; j < 4; j++) fa[nt*4 + j] = oA[nt][j];
    fa[16] = mA; fa[17] = lA;
    float* fb = F + (((wi*2 + 1)*64 + l)*18);
#pragma unroll
    for (int nt = 0; nt < 4; nt++)
#pragma unroll
      for (int j = 0; j < 4; j++) fb[nt*4 + j] = oB[nt][j];
    fb[16] = mB; fb[17] = lB;
  }
  __syncthreads();
  if (g == 0){
    {
      const float* fa = F + (((wi*2 + 0)*64 + l)*18);
      float m1 = fa[16], l1 = fa[17];
      float mM = fmaxf(mA, m1);
      float a0 = exp2f(mA - mM), a1 = exp2f(m1 - mM);
      lA = lA*a0 + l1*a1;
#pragma unroll
      for (int nt = 0; nt < 4; nt++)
#pragma unroll
        for (int j = 0; j < 4; j++) oA[nt][j] = oA[nt][j]*a0 + fa[nt*4+j]*a1;
    }
    {
      const float* fb = F + (((wi*2 + 1)*64 + l)*18);
      float m1 = fb[16], l1 = fb[17];
      float mM = fmaxf(mB, m1);
      float a0 = exp2f(mB - mM), a1 = exp2f(m1 - mM);
      lB = lB*a0 + l1*a1;
#pragma unroll
      for (int nt = 0; nt < 4; nt++)
#pragma unroll
        for (int j = 0; j < 4; j++) oB[nt][j] = oB[nt][j]*a0 + fb[nt*4+j]*a1;
    }
    {
      float inv = 1.0f / lA;
      unsigned short* dst = ao + ((size_t)(b*SEQ + thi*64 + wl))*HID + h*64;
#pragma unroll
      for (int nt = 0; nt < 4; nt++){
        s16x4 ov;
        ov[0] = (short)f2b(oA[nt][0]*inv); ov[1] = (short)f2b(oA[nt][1]*inv);
        ov[2] = (short)f2b(oA[nt][2]*inv); ov[3] = (short)f2b(oA[nt][3]*inv);
        *(s16x4*)(dst + nt*16 + q4*4) = ov;
      }
    }
    {
      float inv = 1.0f / lB;
      unsigned short* dst = ao + ((size_t)(b*SEQ + tlo*64 + wl))*HID + h*64;
#pragma unroll
      for (int nt = 0; nt < 4; nt++){
        s16x4 ov;
        ov[0] = (short)f2b(oB[nt][0]*inv); ov[1] = (short)f2b(oB[nt][1]*inv);
        ov[2] = (short)f2b(oB[nt][2]*inv); ov[3] = (short)f2b(oB[nt][3]*inv);
        *(s16x4*)(dst + nt*16 + q4*4) = ov;
      }
    }
  }
}

// ---------------- output projection GEMM: dbuf gll16 pipeline -> fp32 ----------------
// A = attn bf16 [4096,896], B = Wo bf16 [896,896]. grid (64, 7), block 256.
__global__ __launch_bounds__(256) void out_gemm_kernel(
    const unsigned short* __restrict__ A, const unsigned short* __restrict__ Bw,
    float* __restrict__ out)
{
  __shared__ short As[2][64*64];
  __shared__ short Bs[2][128*64];
  const int tid = threadIdx.x;
  const int bm = blockIdx.x, bn = blockIdx.y;
  const int w = tid >> 6, l = tid & 63, l15 = l & 15, q4 = l >> 4;
  const int wm = w >> 1, wn = w & 1;
  const int lr = l >> 3;
  const int cbg = (l & 7) ^ lr;
  const int sw = l15 & 7;

  fx4 acc[2][4] = {};

  const unsigned short* Ag = A  + (size_t)(bm*64)*HID;
  const unsigned short* Bg = Bw + (size_t)(bn*128)*HID;

  auto issue = [&](int kt, int buf){
    const int kc = kt*64 + cbg*8;
#pragma unroll
    for (int p = 0; p < 2; p++){
      int c = p*4 + w;
      gll16(Ag + (size_t)(c*8 + lr)*HID + kc, &As[buf][c*512]);
    }
#pragma unroll
    for (int p = 0; p < 4; p++){
      int c = p*4 + w;
      gll16(Bg + (size_t)(c*8 + lr)*HID + kc, &Bs[buf][c*512]);
    }
  };

  issue(0, 0);
  for (int kt = 0; kt < 14; kt++){
    const int cur = kt & 1;
    if (kt < 13){
      issue(kt+1, cur^1);
      asm volatile("s_waitcnt vmcnt(6)\n\ts_barrier" ::: "memory");
    } else {
      asm volatile("s_waitcnt vmcnt(0)\n\ts_barrier" ::: "memory");
    }
#pragma unroll
    for (int ks = 0; ks < 2; ks++){
      bf16x8 af[2], bf[4];
#pragma unroll
      for (int mt = 0; mt < 2; mt++){
        int r = wm*32 + mt*16 + l15;
        af[mt] = *(bf16x8*)&As[cur][r*64 + ((ks*4 + q4) ^ sw)*8];
      }
#pragma unroll
      for (int nt = 0; nt < 4; nt++){
        int r = wn*64 + nt*16 + l15;
        bf[nt] = *(bf16x8*)&Bs[cur][r*64 + ((ks*4 + q4) ^ sw)*8];
      }
#pragma unroll
      for (int mt = 0; mt < 2; mt++)
#pragma unroll
        for (int nt = 0; nt < 4; nt++)
          acc[mt][nt] = __builtin_amdgcn_mfma_f32_16x16x32_bf16(af[mt], bf[nt], acc[mt][nt], 0,0,0);
    }
    asm volatile("s_barrier" ::: "memory");
  }

#pragma unroll
  for (int mt = 0; mt < 2; mt++)
#pragma unroll
    for (int j = 0; j < 4; j++){
      int grow = bm*64 + wm*32 + mt*16 + q4*4 + j;
      float* dst = out + (size_t)grow*HID + bn*128 + wn*64;
#pragma unroll
      for (int nt = 0; nt < 4; nt++)
        dst[nt*16 + l15] = acc[mt][nt][j];
    }
}

extern "C" void kernel_launch(void* const* d_in, const int* in_sizes, int n_in,
                              void* d_out, int out_size, void* d_ws, size_t ws_size,
                              hipStream_t stream)
{
  const float* hidden = (const float*)d_in[0];
  const int*   pos    = (const int*)d_in[1];
  const float* Wq = (const float*)d_in[2]; const float* bq = (const float*)d_in[3];
  const float* Wk = (const float*)d_in[4]; const float* bk = (const float*)d_in[5];
  const float* Wv = (const float*)d_in[6]; const float* bv = (const float*)d_in[7];
  const float* Wo = (const float*)d_in[8];

  unsigned short* qws   = (unsigned short*)d_ws;                       // (B,NH,S,64) bf16 (Q pre-scaled)
  unsigned short* kws   = qws   + (size_t)BT*NH*SEQ*64;                // (B,NKV,S,64) bf16
  unsigned short* vtws  = kws   + (size_t)BT*NKV*SEQ*64;               // (B,NKV,S/64,64,64) f16
  unsigned short* wqkv  = vtws  + (size_t)BT*NKV*SEQ*64;               // (1152,896) bf16
  unsigned short* wo16  = wqkv  + (size_t)1152*HID;                    // (896,896) bf16
  unsigned short* h16   = wo16  + (size_t)HID*HID;                     // (4096,896) bf16: hidden, then attn-out
  float2*         tab   = (float2*)(h16 + (size_t)NTOK*HID);           // (2048,32) rope table

  const int nh   = NTOK*HID;
  const int nwq  = HID*HID;
  const int nwkv = 2*64*HID;

  cvt_kernel<<<dim3(448, 6), 256, 0, stream>>>(
      hidden, Wq, Wk, Wv, Wo,
      h16, wqkv, wqkv + nwq, wqkv + nwq + nwkv, wo16,
      nh, nwq, nwkv, nwkv, nwq, tab);

  qkv_gemm_kernel<<<dim3(NTOK/64, 9), 256, 0, stream>>>(
      h16, wqkv, bq, bk, bv, pos, tab, qws, kws, vtws);

  attn_kernel<<<dim3(16, NH, BT), 512, 0, stream>>>(qws, kws, vtws, h16);

  out_gemm_kernel<<<dim3(NTOK/64, 7), 256, 0, stream>>>(h16, wo16, (float*)d_out);
}